// Round 2
// baseline (213.196 us; speedup 1.0000x reference)
//
#include <hip/hip_runtime.h>
#include <stdint.h>

// Shapes: B=8, Nt=Ns=1024, D=128, H=4. All I/O float32.

typedef float f32x16 __attribute__((ext_vector_type(16)));
typedef short s16x8 __attribute__((ext_vector_type(8)));
typedef __bf16 bf16x8 __attribute__((ext_vector_type(8)));

__device__ __forceinline__ f32x16 mfma_bf16(s16x8 a, s16x8 b, f32x16 c) {
  return __builtin_amdgcn_mfma_f32_32x32x16_bf16(
      __builtin_bit_cast(bf16x8, a), __builtin_bit_cast(bf16x8, b), c, 0, 0, 0);
}

__device__ __forceinline__ unsigned short f2bf(float f) {
  union { float f; unsigned int i; } v; v.f = f;
  unsigned int r = (v.i + 0x7fffu + ((v.i >> 16) & 1u)) >> 16;
  return (unsigned short)r;
}
__device__ __forceinline__ s16x8 pack8(float4 a, float4 b) {
  s16x8 r;
  r[0] = (short)f2bf(a.x); r[1] = (short)f2bf(a.y);
  r[2] = (short)f2bf(a.z); r[3] = (short)f2bf(a.w);
  r[4] = (short)f2bf(b.x); r[5] = (short)f2bf(b.y);
  r[6] = (short)f2bf(b.z); r[7] = (short)f2bf(b.w);
  return r;
}
__device__ __forceinline__ f32x16 zero16() {
  f32x16 z;
#pragma unroll
  for (int i = 0; i < 16; ++i) z[i] = 0.f;
  return z;
}

// ---------------- K0: collapsed attention vectors c = W^T @ att ----------------
// c[h][k] = sum_d att[h][d] * W[h*128+d][k]
__global__ void k_cvec(const float* __restrict__ W_tgt,
                       const float* __restrict__ W_src,
                       const float* __restrict__ att_tgt,
                       const float* __restrict__ att_src,
                       float* __restrict__ ws_c) {
  int t = blockIdx.x * 256 + threadIdx.x;  // 0..1023
  int which = t >> 9;                      // 0: tgt, 1: src
  int hk = t & 511;
  int h = hk >> 7, k = hk & 127;
  const float* W = which ? W_src : W_tgt;
  const float* att = which ? att_src : att_tgt;
  float acc = 0.f;
#pragma unroll 4
  for (int d = 0; d < 128; ++d)
    acc += att[h * 128 + d] * W[(h * 128 + d) * 128 + k];
  ws_c[(which ? 512 : 0) + hk] = acc;
}

// ---------------- K1: a_tgtT[b][h][t], a_srcT[b][h][s] (fp32) ----------------
__global__ __launch_bounds__(256) void k_avec(
    const float* __restrict__ x_target,
    const float* __restrict__ x_source,
    const float* __restrict__ ws_c,
    float* __restrict__ a_tgtT, float* __restrict__ a_srcT) {
  int wave = threadIdx.x >> 6, lane = threadIdx.x & 63;
  int row = blockIdx.x * 4 + wave;  // 0..16383
  int is_src = row >> 13;
  int r = row & 8191;
  const float* xp = (is_src ? x_source : x_target) + (size_t)r * 128;
  float2 xv = *(const float2*)(xp + lane * 2);
  const float* c = ws_c + (is_src ? 512 : 0);
  float* out = is_src ? a_srcT : a_tgtT;
#pragma unroll
  for (int h = 0; h < 4; ++h) {
    float p = xv.x * c[h * 128 + lane * 2] + xv.y * c[h * 128 + lane * 2 + 1];
#pragma unroll
    for (int off = 32; off; off >>= 1) p += __shfl_xor(p, off);
    if (lane == 0) out[(((r >> 10) * 4 + h) << 10) | (r & 1023)] = p;
  }
}

// ---------------- K2: h_srcT[b][h][d][s] = (x_source @ W_src^T)^T, bf16 ----------------
__global__ __launch_bounds__(256) void k_hsrc(
    const float* __restrict__ x_source,
    const float* __restrict__ W_src,
    unsigned short* __restrict__ h_srcT) {
  __shared__ unsigned short As[128][136];  // bf16 A tile; reused as transposed C tile
  int mt = blockIdx.x >> 2, nt = blockIdx.x & 3;
  int nbase = nt * 128;
  int b = mt >> 3, sbase = (mt & 7) * 128;
  int tid = threadIdx.x;
#pragma unroll
  for (int c = tid; c < 2048; c += 256) {
    int r = c >> 4, c8 = (c & 15) * 8;
    const float* src = x_source + ((size_t)(mt * 128 + r)) * 128 + c8;
    float4 f0 = *(const float4*)src;
    float4 f1 = *(const float4*)(src + 4);
    *(s16x8*)&As[r][c8] = pack8(f0, f1);
  }
  __syncthreads();
  int w = tid >> 6, lane = tid & 63, tl = lane & 31, q = lane >> 5;
  int wm = w >> 1, wn = w & 1;
  f32x16 acc00 = zero16(), acc01 = zero16(), acc10 = zero16(), acc11 = zero16();
#pragma unroll
  for (int kk = 0; kk < 8; ++kk) {
    int k = kk * 16 + q * 8;
    s16x8 a0 = *(const s16x8*)&As[wm * 64 + tl][k];
    s16x8 a1 = *(const s16x8*)&As[wm * 64 + 32 + tl][k];
    const float* bp0 = W_src + (size_t)(nbase + wn * 64 + tl) * 128 + k;
    const float* bp1 = W_src + (size_t)(nbase + wn * 64 + 32 + tl) * 128 + k;
    s16x8 b0 = pack8(*(const float4*)bp0, *(const float4*)(bp0 + 4));
    s16x8 b1 = pack8(*(const float4*)bp1, *(const float4*)(bp1 + 4));
    acc00 = mfma_bf16(a0, b0, acc00);
    acc01 = mfma_bf16(a0, b1, acc01);
    acc10 = mfma_bf16(a1, b0, acc10);
    acc11 = mfma_bf16(a1, b1, acc11);
  }
  __syncthreads();  // all As reads done
#pragma unroll
  for (int r = 0; r < 16; ++r) {
    int rp = (r & 3) + 8 * (r >> 2) + 4 * q;
    As[wn * 64 + tl][wm * 64 + rp] = f2bf(acc00[r]);
    As[wn * 64 + 32 + tl][wm * 64 + rp] = f2bf(acc01[r]);
    As[wn * 64 + tl][wm * 64 + 32 + rp] = f2bf(acc10[r]);
    As[wn * 64 + 32 + tl][wm * 64 + 32 + rp] = f2bf(acc11[r]);
  }
  __syncthreads();
#pragma unroll
  for (int c = tid; c < 2048; c += 256) {
    int n = c >> 4, m8 = (c & 15) * 8;
    *(uint4*)(h_srcT + ((size_t)(b * 512 + nbase + n)) * 1024 + sbase + m8) =
        *(const uint4*)&As[n][m8];
  }
}

// ---------------- K3: masked-softmax stats m, sc = 0.25/Z per (b,t,h) ----------------
__global__ __launch_bounds__(256) void k_stats(
    const float* __restrict__ adj,
    const float* __restrict__ a_tgtT, const float* __restrict__ a_srcT,
    float* __restrict__ mT, float* __restrict__ scT) {
  int b = blockIdx.x >> 10, t = blockIdx.x & 1023;
  int tid = threadIdx.x;
  float4 av = *(const float4*)(adj + ((size_t)(b * 1024 + t)) * 1024 + tid * 4);
  float adjv[4] = {av.x, av.y, av.z, av.w};
  float m[4], z[4];
#pragma unroll
  for (int h = 0; h < 4; ++h) { m[h] = -1e30f; z[h] = 0.f; }
#pragma unroll
  for (int h = 0; h < 4; ++h) {
    float at = a_tgtT[((b * 4 + h) << 10) | t];
    float4 as4 = *(const float4*)(a_srcT + (((b * 4 + h) << 10) + tid * 4));
    float asv[4] = {as4.x, as4.y, as4.z, as4.w};
#pragma unroll
    for (int j = 0; j < 4; ++j) {
      float x = at + asv[j];
      float lr = fmaf(fminf(x, 0.f), 0.2f, fmaxf(x, 0.f));
      float xe = (adjv[j] != 0.f) ? lr : -1e30f;
      float nm = fmaxf(m[h], xe);
      z[h] = z[h] * __expf(m[h] - nm) + __expf(xe - nm);
      m[h] = nm;
    }
  }
#pragma unroll
  for (int off = 1; off < 64; off <<= 1) {
#pragma unroll
    for (int h = 0; h < 4; ++h) {
      float om = __shfl_xor(m[h], off), oz = __shfl_xor(z[h], off);
      float nm = fmaxf(m[h], om);
      z[h] = z[h] * __expf(m[h] - nm) + oz * __expf(om - nm);
      m[h] = nm;
    }
  }
  __shared__ float sm[4][4], sz[4][4];
  int wv = tid >> 6;
  if ((tid & 63) == 0) {
#pragma unroll
    for (int h = 0; h < 4; ++h) { sm[wv][h] = m[h]; sz[wv][h] = z[h]; }
  }
  __syncthreads();
  if (tid < 4) {
    int h = tid;
    float M = -1e30f, Z = 0.f;
#pragma unroll
    for (int w = 0; w < 4; ++w) {
      float nm = fmaxf(M, sm[w][h]);
      Z = Z * __expf(M - nm) + sz[w][h] * __expf(sm[w][h] - nm);
      M = nm;
    }
    bool dead = M < -1e29f;
    int idx = ((b * 4 + h) << 10) | t;
    mT[idx] = dead ? 0.f : M;
    scT[idx] = dead ? 0.f : 0.25f / Z;
  }
}

// ---------------- K4: fused attention einsum + head-mean + bias -> out_mean fp32 ----
// grid: b(8) x t-tile(32 of 32 rows); 512 threads = 8 waves: head = w&3, s-half = w>>2.
__global__ __launch_bounds__(512) void k_attn(
    const float* __restrict__ adj,
    const unsigned short* __restrict__ h_srcT,
    const float* __restrict__ a_tgtT, const float* __restrict__ a_srcT,
    const float* __restrict__ mT, const float* __restrict__ scT,
    const float* __restrict__ gat_bias,
    float* __restrict__ out_mean) {
  __shared__ float smem[16384];  // first 4096: a_src staging; later: [4][32][128] reduce
  int b = blockIdx.x >> 5, tt = blockIdx.x & 31;
  int tbase = tt * 32;
  int tid = threadIdx.x;
  for (int i = tid; i < 4096; i += 512) smem[i] = a_srcT[(b << 12) + i];
  int w = tid >> 6, lane = tid & 63;
  int head = w & 3, shalf = w >> 2;
  int tl = lane & 31, q = lane >> 5;
  int t = tbase + tl;
  int bh = (b * 4 + head) << 10;
  float at = a_tgtT[bh | t];
  float mm = mT[bh | t];
  float sc = scT[bh | t];
  __syncthreads();
  f32x16 acc[4];
#pragma unroll
  for (int i = 0; i < 4; ++i) acc[i] = zero16();
  const float* asl = smem + (head << 10);
  const unsigned short* hbase = h_srcT + (((size_t)(b * 512 + head * 128 + tl)) << 10);
  const float* adjrow = adj + (((size_t)(b * 1024 + t)) << 10);
  int s0base = shalf * 512;
#pragma unroll 2
  for (int kk = 0; kk < 32; ++kk) {
    int sA = s0base + kk * 16 + q * 8;
    float4 av0 = *(const float4*)(adjrow + sA);
    float4 av1 = *(const float4*)(adjrow + sA + 4);
    float4 as0 = *(const float4*)(asl + sA);
    float4 as1 = *(const float4*)(asl + sA + 4);
    float asv[8] = {as0.x, as0.y, as0.z, as0.w, as1.x, as1.y, as1.z, as1.w};
    float avv[8] = {av0.x, av0.y, av0.z, av0.w, av1.x, av1.y, av1.z, av1.w};
    s16x8 af;
#pragma unroll
    for (int j = 0; j < 8; ++j) {
      float x = at + asv[j];
      float lr = fmaf(fminf(x, 0.f), 0.2f, fmaxf(x, 0.f));
      float p = (avv[j] != 0.f) ? __expf(lr - mm) * sc : 0.f;
      af[j] = (short)f2bf(p);
    }
    const unsigned short* hp = hbase + sA;
    s16x8 b0 = *(const s16x8*)(hp);
    s16x8 b1 = *(const s16x8*)(hp + 32 * 1024);
    s16x8 b2 = *(const s16x8*)(hp + 64 * 1024);
    s16x8 b3 = *(const s16x8*)(hp + 96 * 1024);
    acc[0] = mfma_bf16(af, b0, acc[0]);
    acc[1] = mfma_bf16(af, b1, acc[1]);
    acc[2] = mfma_bf16(af, b2, acc[2]);
    acc[3] = mfma_bf16(af, b3, acc[3]);
  }
  __syncthreads();  // done with a_src staging; reuse smem as [4][32][128]
  float* red = smem;
  if (w < 4) {
#pragma unroll
    for (int dt = 0; dt < 4; ++dt)
#pragma unroll
      for (int r = 0; r < 16; ++r) {
        int rp = (r & 3) + 8 * (r >> 2) + 4 * q;
        red[((head * 32 + rp) << 7) + dt * 32 + tl] = acc[dt][r];
      }
  }
  __syncthreads();
  if (w >= 4) {
#pragma unroll
    for (int dt = 0; dt < 4; ++dt)
#pragma unroll
      for (int r = 0; r < 16; ++r) {
        int rp = (r & 3) + 8 * (r >> 2) + 4 * q;
        red[((head * 32 + rp) << 7) + dt * 32 + tl] += acc[dt][r];
      }
  }
  __syncthreads();
  for (int i = tid; i < 4096; i += 512) {
    int trow = i >> 7, d = i & 127;
    float s = red[((0 * 32 + trow) << 7) + d] + red[((1 * 32 + trow) << 7) + d] +
              red[((2 * 32 + trow) << 7) + d] + red[((3 * 32 + trow) << 7) + d];
    out_mean[(((size_t)(b * 1024 + tbase + trow)) << 7) + d] = s + gat_bias[d];
  }
}

// ---------------- K5: LN1 + SwiGLU FFN + LN2 -> fp32 out ----------------
__global__ __launch_bounds__(256) void k_ffn(
    const float* __restrict__ x_target,
    const float* __restrict__ out_mean,
    const float* __restrict__ ln1_g, const float* __restrict__ ln1_b,
    const float* __restrict__ W_gv, const float* __restrict__ W_out,
    const float* __restrict__ ln2_g, const float* __restrict__ ln2_b,
    float* __restrict__ out) {
  __shared__ unsigned short x1s[32][136];  // bf16 LN1 output (GEMM input)
  __shared__ float x1f[32][128];           // fp32 LN1 output (residual)
  __shared__ unsigned short hids[32][136];
  __shared__ float yred[32][128];
  int tid = threadIdx.x;
  int rbase = blockIdx.x * 32;
  int row = tid >> 3, j8 = tid & 7, k0 = j8 * 16;
  size_t gr = (size_t)rbase + row;
  // phase 1: u = x_target + out_mean; LN1 -> x1
  {
    const float* xp = x_target + gr * 128 + k0;
    const float* op = out_mean + gr * 128 + k0;
    float u[16];
#pragma unroll
    for (int i = 0; i < 16; i += 4) {
      float4 xa = *(const float4*)(xp + i);
      float4 oa = *(const float4*)(op + i);
      u[i] = xa.x + oa.x; u[i + 1] = xa.y + oa.y;
      u[i + 2] = xa.z + oa.z; u[i + 3] = xa.w + oa.w;
    }
    float s = 0.f, ss = 0.f;
#pragma unroll
    for (int i = 0; i < 16; ++i) { s += u[i]; ss += u[i] * u[i]; }
#pragma unroll
    for (int off = 1; off < 8; off <<= 1) { s += __shfl_xor(s, off); ss += __shfl_xor(ss, off); }
    float mu = s * (1.f / 128.f);
    float var = ss * (1.f / 128.f) - mu * mu;
    float rstd = rsqrtf(var + 1e-5f);
#pragma unroll
    for (int i = 0; i < 16; ++i) {
      float xv = (u[i] - mu) * rstd * ln1_g[k0 + i] + ln1_b[k0 + i];
      x1s[row][k0 + i] = f2bf(xv);
      x1f[row][k0 + i] = xv;
    }
  }
  __syncthreads();
  int w = tid >> 6, lane = tid & 63, tl = lane & 31, q = lane >> 5;
  // GEMM1: x1 @ W_gv^T -> val (rows 0..127), gate (rows 128..255)
  f32x16 accv = zero16(), accg = zero16();
  const float* bv = W_gv + (size_t)(w * 32 + tl) * 128;
  const float* bg = W_gv + (size_t)(128 + w * 32 + tl) * 128;
#pragma unroll
  for (int kk = 0; kk < 8; ++kk) {
    int k = kk * 16 + q * 8;
    s16x8 a = *(const s16x8*)&x1s[tl][k];
    s16x8 wv8 = pack8(*(const float4*)(bv + k), *(const float4*)(bv + k + 4));
    s16x8 wg8 = pack8(*(const float4*)(bg + k), *(const float4*)(bg + k + 4));
    accv = mfma_bf16(a, wv8, accv);
    accg = mfma_bf16(a, wg8, accg);
  }
#pragma unroll
  for (int r = 0; r < 16; ++r) {
    int m = (r & 3) + 8 * (r >> 2) + 4 * q;
    float g = accg[r];
    float sig = 1.f / (1.f + __expf(-g));
    hids[m][w * 32 + tl] = f2bf(accv[r] * g * sig);
  }
  __syncthreads();
  // GEMM2: hidden @ W_out^T
  f32x16 acco = zero16();
  const float* bo = W_out + (size_t)(w * 32 + tl) * 128;
#pragma unroll
  for (int kk = 0; kk < 8; ++kk) {
    int k = kk * 16 + q * 8;
    s16x8 a = *(const s16x8*)&hids[tl][k];
    s16x8 wo8 = pack8(*(const float4*)(bo + k), *(const float4*)(bo + k + 4));
    acco = mfma_bf16(a, wo8, acco);
  }
#pragma unroll
  for (int r = 0; r < 16; ++r) {
    int m = (r & 3) + 8 * (r >> 2) + 4 * q;
    yred[m][w * 32 + tl] = x1f[m][w * 32 + tl] + acco[r];
  }
  __syncthreads();
  // LN2 + store
  {
    float y[16];
#pragma unroll
    for (int i = 0; i < 16; ++i) y[i] = yred[row][k0 + i];
    float s = 0.f, ss = 0.f;
#pragma unroll
    for (int i = 0; i < 16; ++i) { s += y[i]; ss += y[i] * y[i]; }
#pragma unroll
    for (int off = 1; off < 8; off <<= 1) { s += __shfl_xor(s, off); ss += __shfl_xor(ss, off); }
    float mu = s * (1.f / 128.f);
    float var = ss * (1.f / 128.f) - mu * mu;
    float rstd = rsqrtf(var + 1e-5f);
#pragma unroll
    for (int i = 0; i < 16; i += 4) {
      float4 o;
      o.x = (y[i] - mu) * rstd * ln2_g[k0 + i] + ln2_b[k0 + i];
      o.y = (y[i + 1] - mu) * rstd * ln2_g[k0 + i + 1] + ln2_b[k0 + i + 1];
      o.z = (y[i + 2] - mu) * rstd * ln2_g[k0 + i + 2] + ln2_b[k0 + i + 2];
      o.w = (y[i + 3] - mu) * rstd * ln2_g[k0 + i + 3] + ln2_b[k0 + i + 3];
      *(float4*)(out + gr * 128 + k0 + i) = o;
    }
  }
}

// ---------------- launch ----------------
extern "C" void kernel_launch(void* const* d_in, const int* in_sizes, int n_in,
                              void* d_out, int out_size, void* d_ws, size_t ws_size,
                              hipStream_t stream) {
  const float* x_target = (const float*)d_in[0];
  const float* adj      = (const float*)d_in[1];
  const float* x_source = (const float*)d_in[2];
  const float* W_src    = (const float*)d_in[3];
  const float* W_tgt    = (const float*)d_in[4];
  const float* att_src  = (const float*)d_in[5];
  const float* att_tgt  = (const float*)d_in[6];
  const float* gat_bias = (const float*)d_in[7];
  const float* ln1_g    = (const float*)d_in[8];
  const float* ln1_b    = (const float*)d_in[9];
  const float* W_gv     = (const float*)d_in[10];
  const float* W_out    = (const float*)d_in[11];
  const float* ln2_g    = (const float*)d_in[12];
  const float* ln2_b    = (const float*)d_in[13];

  float* ws_f = (float*)d_ws;
  // fp32 workspace layout (element offsets)
  const size_t OFF_C   = 0;        // c_tgt[512] + c_src[512]
  const size_t OFF_ATG = 1024;     // a_tgtT [8][4][1024]
  const size_t OFF_ASR = 33792;    // a_srcT [8][4][1024]
  const size_t OFF_M   = 66560;    // mT
  const size_t OFF_SC  = 99328;    // scT
  const size_t OFF_OM  = 132096;   // out_mean [8192][128]
  unsigned short* h_srcT = (unsigned short*)(ws_f + OFF_OM + (size_t)8192 * 128);

  k_cvec<<<4, 256, 0, stream>>>(W_tgt, W_src, att_tgt, att_src, ws_f + OFF_C);
  k_avec<<<4096, 256, 0, stream>>>(x_target, x_source, ws_f + OFF_C,
                                   ws_f + OFF_ATG, ws_f + OFF_ASR);
  k_hsrc<<<256, 256, 0, stream>>>(x_source, W_src, h_srcT);
  k_stats<<<8192, 256, 0, stream>>>(adj, ws_f + OFF_ATG, ws_f + OFF_ASR,
                                    ws_f + OFF_M, ws_f + OFF_SC);
  k_attn<<<256, 512, 0, stream>>>(adj, h_srcT, ws_f + OFF_ATG, ws_f + OFF_ASR,
                                  ws_f + OFF_M, ws_f + OFF_SC, gat_bias,
                                  ws_f + OFF_OM);
  k_ffn<<<256, 256, 0, stream>>>(x_target, ws_f + OFF_OM, ln1_g, ln1_b,
                                 W_gv, W_out, ln2_g, ln2_b,
                                 (float*)d_out);
}

// Round 3
// 190.728 us; speedup vs baseline: 1.1178x; 1.1178x over previous
//
#include <hip/hip_runtime.h>
#include <stdint.h>

// Shapes: B=8, Nt=Ns=1024, D=128, H=4. All I/O float32.

typedef float f32x16 __attribute__((ext_vector_type(16)));
typedef short s16x8 __attribute__((ext_vector_type(8)));
typedef __bf16 bf16x8 __attribute__((ext_vector_type(8)));

__device__ __forceinline__ f32x16 mfma_bf16(s16x8 a, s16x8 b, f32x16 c) {
  return __builtin_amdgcn_mfma_f32_32x32x16_bf16(
      __builtin_bit_cast(bf16x8, a), __builtin_bit_cast(bf16x8, b), c, 0, 0, 0);
}

__device__ __forceinline__ unsigned short f2bf(float f) {
  union { float f; unsigned int i; } v; v.f = f;
  return (unsigned short)((v.i + 0x8000u) >> 16);  // round-to-nearest (ties away)
}
__device__ __forceinline__ s16x8 pack8(float4 a, float4 b) {
  s16x8 r;
  r[0] = (short)f2bf(a.x); r[1] = (short)f2bf(a.y);
  r[2] = (short)f2bf(a.z); r[3] = (short)f2bf(a.w);
  r[4] = (short)f2bf(b.x); r[5] = (short)f2bf(b.y);
  r[6] = (short)f2bf(b.z); r[7] = (short)f2bf(b.w);
  return r;
}
__device__ __forceinline__ f32x16 zero16() {
  f32x16 z;
#pragma unroll
  for (int i = 0; i < 16; ++i) z[i] = 0.f;
  return z;
}
__device__ __forceinline__ float lrelu(float v) {
  return fmaf(fminf(v, 0.f), 0.2f, fmaxf(v, 0.f));
}

// ---------------- K0: collapsed attention vectors c = W^T @ att ----------------
__global__ void k_cvec(const float* __restrict__ W_tgt,
                       const float* __restrict__ W_src,
                       const float* __restrict__ att_tgt,
                       const float* __restrict__ att_src,
                       float* __restrict__ ws_c) {
  int t = blockIdx.x * 256 + threadIdx.x;  // 0..1023
  int which = t >> 9;
  int hk = t & 511;
  int h = hk >> 7, k = hk & 127;
  const float* W = which ? W_src : W_tgt;
  const float* att = which ? att_src : att_tgt;
  float acc = 0.f;
#pragma unroll 4
  for (int d = 0; d < 128; ++d)
    acc += att[h * 128 + d] * W[(h * 128 + d) * 128 + k];
  ws_c[(which ? 512 : 0) + hk] = acc;
}

// ---------------- K0b: pack FFN weights to bf16 ----------------
__global__ void k_wpack(const float* __restrict__ W_gv,
                        const float* __restrict__ W_out,
                        unsigned short* __restrict__ wp) {
  int i = blockIdx.x * 256 + threadIdx.x;  // 0..49151
  float v = (i < 32768) ? W_gv[i] : W_out[i - 32768];
  wp[i] = f2bf(v);
}

// ---------------- K1: a_tgtT[b][h][t], a_srcT[b][h][s] (fp32) ----------------
__global__ __launch_bounds__(256) void k_avec(
    const float* __restrict__ x_target,
    const float* __restrict__ x_source,
    const float* __restrict__ ws_c,
    float* __restrict__ a_tgtT, float* __restrict__ a_srcT) {
  int wave = threadIdx.x >> 6, lane = threadIdx.x & 63;
  int row = blockIdx.x * 4 + wave;  // 0..16383
  int is_src = row >> 13;
  int r = row & 8191;
  const float* xp = (is_src ? x_source : x_target) + (size_t)r * 128;
  float2 xv = *(const float2*)(xp + lane * 2);
  const float* c = ws_c + (is_src ? 512 : 0);
  float* out = is_src ? a_srcT : a_tgtT;
#pragma unroll
  for (int h = 0; h < 4; ++h) {
    float p = xv.x * c[h * 128 + lane * 2] + xv.y * c[h * 128 + lane * 2 + 1];
#pragma unroll
    for (int off = 32; off; off >>= 1) p += __shfl_xor(p, off);
    if (lane == 0) out[(((r >> 10) * 4 + h) << 10) | (r & 1023)] = p;
  }
}

// ---------------- K2: h_srcT[b][h][d][s] = (x_source @ W_src^T)^T, bf16 ----------------
__global__ __launch_bounds__(256) void k_hsrc(
    const float* __restrict__ x_source,
    const float* __restrict__ W_src,
    unsigned short* __restrict__ h_srcT) {
  __shared__ unsigned short As[128][136];
  int mt = blockIdx.x >> 2, nt = blockIdx.x & 3;
  int nbase = nt * 128;
  int b = mt >> 3, sbase = (mt & 7) * 128;
  int tid = threadIdx.x;
#pragma unroll
  for (int c = tid; c < 2048; c += 256) {
    int r = c >> 4, c8 = (c & 15) * 8;
    const float* src = x_source + ((size_t)(mt * 128 + r)) * 128 + c8;
    *(s16x8*)&As[r][c8] = pack8(*(const float4*)src, *(const float4*)(src + 4));
  }
  __syncthreads();
  int w = tid >> 6, lane = tid & 63, tl = lane & 31, q = lane >> 5;
  int wm = w >> 1, wn = w & 1;
  f32x16 acc00 = zero16(), acc01 = zero16(), acc10 = zero16(), acc11 = zero16();
#pragma unroll
  for (int kk = 0; kk < 8; ++kk) {
    int k = kk * 16 + q * 8;
    s16x8 a0 = *(const s16x8*)&As[wm * 64 + tl][k];
    s16x8 a1 = *(const s16x8*)&As[wm * 64 + 32 + tl][k];
    const float* bp0 = W_src + (size_t)(nbase + wn * 64 + tl) * 128 + k;
    const float* bp1 = W_src + (size_t)(nbase + wn * 64 + 32 + tl) * 128 + k;
    s16x8 b0 = pack8(*(const float4*)bp0, *(const float4*)(bp0 + 4));
    s16x8 b1 = pack8(*(const float4*)bp1, *(const float4*)(bp1 + 4));
    acc00 = mfma_bf16(a0, b0, acc00);
    acc01 = mfma_bf16(a0, b1, acc01);
    acc10 = mfma_bf16(a1, b0, acc10);
    acc11 = mfma_bf16(a1, b1, acc11);
  }
  __syncthreads();
#pragma unroll
  for (int r = 0; r < 16; ++r) {
    int rp = (r & 3) + 8 * (r >> 2) + 4 * q;
    As[wn * 64 + tl][wm * 64 + rp] = f2bf(acc00[r]);
    As[wn * 64 + 32 + tl][wm * 64 + rp] = f2bf(acc01[r]);
    As[wn * 64 + tl][wm * 64 + 32 + rp] = f2bf(acc10[r]);
    As[wn * 64 + 32 + tl][wm * 64 + 32 + rp] = f2bf(acc11[r]);
  }
  __syncthreads();
#pragma unroll
  for (int c = tid; c < 2048; c += 256) {
    int n = c >> 4, m8 = (c & 15) * 8;
    *(uint4*)(h_srcT + ((size_t)(b * 512 + nbase + n)) * 1024 + sbase + m8) =
        *(const uint4*)&As[n][m8];
  }
}

// ---------------- K3: fused stats + attention einsum + head-mean + bias ----------------
// grid 256 = b(xcd-swizzled, &7) x t-tile(>>3); 1024 threads = 16 waves (head, s-quarter)
__global__ __launch_bounds__(1024, 4) void k_attn(
    const float* __restrict__ adj,
    const unsigned short* __restrict__ h_srcT,
    const float* __restrict__ a_tgtT, const float* __restrict__ a_srcT,
    const float* __restrict__ gat_bias,
    float* __restrict__ out_mean) {
  __shared__ float asb[4096];          // a_src[h][s], 16 KB
  __shared__ float red[4][32][128];    // per-head partial out, 64 KB
  __shared__ unsigned int bmask[32][33];
  __shared__ float atb[4][32], mb[4][32], scb[4][32];
  __shared__ float zpart[4][4][32];

  int b = blockIdx.x & 7, tt = blockIdx.x >> 3;
  int tbase = tt * 32;
  int tid = threadIdx.x;
  int w = tid >> 6, lane = tid & 63;

  // P0: stage a_src
  {
    float4 v = *(const float4*)(a_srcT + (b << 12) + tid * 4);
    *(float4*)&asb[tid * 4] = v;
  }
  __syncthreads();

  // P1: stream adj -> bitmask + masked max of a_src per (row, head)
  {
    int half = lane >> 5, sl = lane & 31;
    int r = 2 * w + half;
    int t = tbase + r;
    const float* adjrow = adj + ((size_t)(b * 1024 + t) << 10);
    float at[4], amax[4];
#pragma unroll
    for (int h = 0; h < 4; ++h) {
      at[h] = a_tgtT[((b * 4 + h) << 10) | t];
      amax[h] = -3e38f;
    }
#pragma unroll 4
    for (int j = 0; j < 32; ++j) {
      int s = j * 32 + sl;
      float A = adjrow[s];
      bool alive = (A != 0.f);
      unsigned long long bal = __ballot(alive);
      if (sl == 0) bmask[r][j] = (unsigned int)(bal >> (half * 32));
      if (alive) {
#pragma unroll
        for (int h = 0; h < 4; ++h) amax[h] = fmaxf(amax[h], asb[(h << 10) + s]);
      }
    }
#pragma unroll
    for (int off = 1; off < 32; off <<= 1)
#pragma unroll
      for (int h = 0; h < 4; ++h) amax[h] = fmaxf(amax[h], __shfl_xor(amax[h], off));
    if (sl == 0) {
#pragma unroll
      for (int h = 0; h < 4; ++h) {
        atb[h][r] = at[h];
        mb[h][r] = (amax[h] > -1e37f) ? lrelu(at[h] + amax[h]) : 0.f;
      }
    }
  }
  __syncthreads();

  // P2: MFMA loop. wave w: head = w&3, s-quarter = w>>2 (256 s each)
  int head = w & 3, sq = w >> 2;
  int tl = lane & 31, q = lane >> 5;
  float at = atb[head][tl];
  float mm = mb[head][tl];
  f32x16 acc[4];
#pragma unroll
  for (int i = 0; i < 4; ++i) acc[i] = zero16();
  float z = 0.f;
  const float* asl = asb + (head << 10);
  const unsigned short* hbase =
      h_srcT + (((size_t)(b * 512 + head * 128 + tl)) << 10);
#pragma unroll 2
  for (int kk = 0; kk < 16; ++kk) {
    int sA = sq * 256 + kk * 16 + q * 8;
    const unsigned short* hp = hbase + sA;
    s16x8 b0 = *(const s16x8*)(hp);
    s16x8 b1 = *(const s16x8*)(hp + 32 * 1024);
    s16x8 b2 = *(const s16x8*)(hp + 64 * 1024);
    s16x8 b3 = *(const s16x8*)(hp + 96 * 1024);
    float4 as0 = *(const float4*)(asl + sA);
    float4 as1 = *(const float4*)(asl + sA + 4);
    unsigned int wbits = bmask[tl][sA >> 5] >> (sA & 31);
    float asv[8] = {as0.x, as0.y, as0.z, as0.w, as1.x, as1.y, as1.z, as1.w};
    s16x8 af;
#pragma unroll
    for (int j = 0; j < 8; ++j) {
      float e = __expf(lrelu(at + asv[j]) - mm);
      float p = ((wbits >> j) & 1u) ? e : 0.f;
      z += p;
      af[j] = (short)f2bf(p);
    }
    acc[0] = mfma_bf16(af, b0, acc[0]);
    acc[1] = mfma_bf16(af, b1, acc[1]);
    acc[2] = mfma_bf16(af, b2, acc[2]);
    acc[3] = mfma_bf16(af, b3, acc[3]);
  }
  // P3: Z reduction -> sc = 0.25/Z
  z += __shfl_xor(z, 32);
  if (q == 0) zpart[head][sq][tl] = z;
  __syncthreads();
  if (tid < 128) {
    int h = tid >> 5, r = tid & 31;
    float Z = zpart[h][0][r] + zpart[h][1][r] + zpart[h][2][r] + zpart[h][3][r];
    scb[h][r] = (Z > 0.f) ? 0.25f / Z : 0.f;
  }
  // P4: staged accumulator reduction over s-quarters
#pragma unroll
  for (int sqi = 0; sqi < 4; ++sqi) {
    __syncthreads();
    if (sq == sqi) {
#pragma unroll
      for (int dt = 0; dt < 4; ++dt)
#pragma unroll
        for (int r = 0; r < 16; ++r) {
          int rp = (r & 3) + 8 * (r >> 2) + 4 * q;
          if (sqi == 0)
            red[head][rp][dt * 32 + tl] = acc[dt][r];
          else
            red[head][rp][dt * 32 + tl] += acc[dt][r];
        }
    }
  }
  __syncthreads();
  // final: head-mean with per-(t,h) scale + bias
#pragma unroll
  for (int i = tid; i < 4096; i += 1024) {
    int r = i >> 7, d = i & 127;
    float s = red[0][r][d] * scb[0][r] + red[1][r][d] * scb[1][r] +
              red[2][r][d] * scb[2][r] + red[3][r][d] * scb[3][r];
    out_mean[(((size_t)(b * 1024 + tbase + r)) << 7) + d] = s + gat_bias[d];
  }
}

// ---------------- K5: LN1 + SwiGLU FFN + LN2 -> fp32 out ----------------
__global__ __launch_bounds__(256) void k_ffn(
    const float* __restrict__ x_target,
    const float* __restrict__ out_mean,
    const float* __restrict__ ln1_g, const float* __restrict__ ln1_b,
    const unsigned short* __restrict__ wp,   // bf16: W_gv [256][128], W_out [128][128]
    const float* __restrict__ ln2_g, const float* __restrict__ ln2_b,
    float* __restrict__ out) {
  __shared__ unsigned short x1s[32][136];
  __shared__ float x1f[32][128];
  __shared__ unsigned short hids[32][136];
  __shared__ float yred[32][128];
  int tid = threadIdx.x;
  int rbase = blockIdx.x * 32;
  int row = tid >> 3, j8 = tid & 7, k0 = j8 * 16;
  size_t gr = (size_t)rbase + row;
  {
    const float* xp = x_target + gr * 128 + k0;
    const float* op = out_mean + gr * 128 + k0;
    float u[16];
#pragma unroll
    for (int i = 0; i < 16; i += 4) {
      float4 xa = *(const float4*)(xp + i);
      float4 oa = *(const float4*)(op + i);
      u[i] = xa.x + oa.x; u[i + 1] = xa.y + oa.y;
      u[i + 2] = xa.z + oa.z; u[i + 3] = xa.w + oa.w;
    }
    float s = 0.f, ss = 0.f;
#pragma unroll
    for (int i = 0; i < 16; ++i) { s += u[i]; ss += u[i] * u[i]; }
#pragma unroll
    for (int off = 1; off < 8; off <<= 1) { s += __shfl_xor(s, off); ss += __shfl_xor(ss, off); }
    float mu = s * (1.f / 128.f);
    float var = ss * (1.f / 128.f) - mu * mu;
    float rstd = rsqrtf(var + 1e-5f);
#pragma unroll
    for (int i = 0; i < 16; ++i) {
      float xv = (u[i] - mu) * rstd * ln1_g[k0 + i] + ln1_b[k0 + i];
      x1s[row][k0 + i] = f2bf(xv);
      x1f[row][k0 + i] = xv;
    }
  }
  __syncthreads();
  int w = tid >> 6, lane = tid & 63, tl = lane & 31, q = lane >> 5;
  f32x16 accv = zero16(), accg = zero16();
  const unsigned short* bv = wp + (size_t)(w * 32 + tl) * 128;
  const unsigned short* bg = wp + (size_t)(128 + w * 32 + tl) * 128;
#pragma unroll
  for (int kk = 0; kk < 8; ++kk) {
    int k = kk * 16 + q * 8;
    s16x8 a = *(const s16x8*)&x1s[tl][k];
    accv = mfma_bf16(a, *(const s16x8*)(bv + k), accv);
    accg = mfma_bf16(a, *(const s16x8*)(bg + k), accg);
  }
#pragma unroll
  for (int r = 0; r < 16; ++r) {
    int m = (r & 3) + 8 * (r >> 2) + 4 * q;
    float g = accg[r];
    float sig = 1.f / (1.f + __expf(-g));
    hids[m][w * 32 + tl] = f2bf(accv[r] * g * sig);
  }
  __syncthreads();
  f32x16 acco = zero16();
  const unsigned short* bo = wp + 32768 + (size_t)(w * 32 + tl) * 128;
#pragma unroll
  for (int kk = 0; kk < 8; ++kk) {
    int k = kk * 16 + q * 8;
    acco = mfma_bf16(*(const s16x8*)&hids[tl][k], *(const s16x8*)(bo + k), acco);
  }
#pragma unroll
  for (int r = 0; r < 16; ++r) {
    int m = (r & 3) + 8 * (r >> 2) + 4 * q;
    yred[m][w * 32 + tl] = x1f[m][w * 32 + tl] + acco[r];
  }
  __syncthreads();
  {
    float y[16];
#pragma unroll
    for (int i = 0; i < 16; ++i) y[i] = yred[row][k0 + i];
    float s = 0.f, ss = 0.f;
#pragma unroll
    for (int i = 0; i < 16; ++i) { s += y[i]; ss += y[i] * y[i]; }
#pragma unroll
    for (int off = 1; off < 8; off <<= 1) { s += __shfl_xor(s, off); ss += __shfl_xor(ss, off); }
    float mu = s * (1.f / 128.f);
    float var = ss * (1.f / 128.f) - mu * mu;
    float rstd = rsqrtf(var + 1e-5f);
#pragma unroll
    for (int i = 0; i < 16; i += 4) {
      float4 o;
      o.x = (y[i] - mu) * rstd * ln2_g[k0 + i] + ln2_b[k0 + i];
      o.y = (y[i + 1] - mu) * rstd * ln2_g[k0 + i + 1] + ln2_b[k0 + i + 1];
      o.z = (y[i + 2] - mu) * rstd * ln2_g[k0 + i + 2] + ln2_b[k0 + i + 2];
      o.w = (y[i + 3] - mu) * rstd * ln2_g[k0 + i + 3] + ln2_b[k0 + i + 3];
      *(float4*)(out + gr * 128 + k0 + i) = o;
    }
  }
}

// ---------------- launch ----------------
extern "C" void kernel_launch(void* const* d_in, const int* in_sizes, int n_in,
                              void* d_out, int out_size, void* d_ws, size_t ws_size,
                              hipStream_t stream) {
  const float* x_target = (const float*)d_in[0];
  const float* adj      = (const float*)d_in[1];
  const float* x_source = (const float*)d_in[2];
  const float* W_src    = (const float*)d_in[3];
  const float* W_tgt    = (const float*)d_in[4];
  const float* att_src  = (const float*)d_in[5];
  const float* att_tgt  = (const float*)d_in[6];
  const float* gat_bias = (const float*)d_in[7];
  const float* ln1_g    = (const float*)d_in[8];
  const float* ln1_b    = (const float*)d_in[9];
  const float* W_gv     = (const float*)d_in[10];
  const float* W_out    = (const float*)d_in[11];
  const float* ln2_g    = (const float*)d_in[12];
  const float* ln2_b    = (const float*)d_in[13];

  float* ws_f = (float*)d_ws;
  const size_t OFF_C   = 0;        // 1024 f
  const size_t OFF_ATG = 1024;     // a_tgtT [8][4][1024]
  const size_t OFF_ASR = 33792;    // a_srcT [8][4][1024]
  const size_t OFF_OM  = 66560;    // out_mean [8192][128]
  unsigned short* h_srcT = (unsigned short*)(ws_f + OFF_OM + (size_t)8192 * 128);
  unsigned short* wp = h_srcT + (size_t)8 * 512 * 1024;  // 49152 bf16

  k_cvec<<<4, 256, 0, stream>>>(W_tgt, W_src, att_tgt, att_src, ws_f + OFF_C);
  k_wpack<<<192, 256, 0, stream>>>(W_gv, W_out, wp);
  k_avec<<<4096, 256, 0, stream>>>(x_target, x_source, ws_f + OFF_C,
                                   ws_f + OFF_ATG, ws_f + OFF_ASR);
  k_hsrc<<<256, 256, 0, stream>>>(x_source, W_src, h_srcT);
  k_attn<<<256, 1024, 0, stream>>>(adj, h_srcT, ws_f + OFF_ATG, ws_f + OFF_ASR,
                                   gat_bias, ws_f + OFF_OM);
  k_ffn<<<256, 256, 0, stream>>>(x_target, ws_f + OFF_OM, ln1_g, ln1_b,
                                 wp, ln2_g, ln2_b, (float*)d_out);
}

// Round 4
// 163.423 us; speedup vs baseline: 1.3046x; 1.1671x over previous
//
#include <hip/hip_runtime.h>
#include <stdint.h>

// Shapes: B=8, Nt=Ns=1024, D=128, H=4. All I/O float32.

typedef float f32x16 __attribute__((ext_vector_type(16)));
typedef short s16x8 __attribute__((ext_vector_type(8)));
typedef __bf16 bf16x8 __attribute__((ext_vector_type(8)));

__device__ __forceinline__ f32x16 mfma_bf16(s16x8 a, s16x8 b, f32x16 c) {
  return __builtin_amdgcn_mfma_f32_32x32x16_bf16(
      __builtin_bit_cast(bf16x8, a), __builtin_bit_cast(bf16x8, b), c, 0, 0, 0);
}

__device__ __forceinline__ unsigned short f2bf(float f) {
  union { float f; unsigned int i; } v; v.f = f;
  return (unsigned short)((v.i + 0x8000u) >> 16);
}
__device__ __forceinline__ s16x8 pack8(float4 a, float4 b) {
  s16x8 r;
  r[0] = (short)f2bf(a.x); r[1] = (short)f2bf(a.y);
  r[2] = (short)f2bf(a.z); r[3] = (short)f2bf(a.w);
  r[4] = (short)f2bf(b.x); r[5] = (short)f2bf(b.y);
  r[6] = (short)f2bf(b.z); r[7] = (short)f2bf(b.w);
  return r;
}
__device__ __forceinline__ f32x16 zero16() {
  f32x16 z;
#pragma unroll
  for (int i = 0; i < 16; ++i) z[i] = 0.f;
  return z;
}
__device__ __forceinline__ float lrelu(float v) {
  return fmaf(fminf(v, 0.f), 0.2f, fmaxf(v, 0.f));
}

// ---------------- K_prep: cvec + FFN weight pack + W_src pack ----------------
// blocks 0..3: c[h][k] = sum_d att[h][d] * W[h*128+d][k]
// blocks 4..195: wpP[mat][k/8][n][8] bf16 from W_gv/W_out
// blocks 196..451: W_srcP[k/8][n][8] bf16 from W_src
__global__ __launch_bounds__(256) void k_prep(
    const float* __restrict__ W_tgt, const float* __restrict__ W_src,
    const float* __restrict__ att_tgt, const float* __restrict__ att_src,
    const float* __restrict__ W_gv, const float* __restrict__ W_out,
    float* __restrict__ ws_c, unsigned short* __restrict__ wpP,
    unsigned short* __restrict__ W_srcP) {
  int blk = blockIdx.x, tid = threadIdx.x;
  if (blk < 4) {
    int t = blk * 256 + tid;  // 0..1023
    int which = t >> 9;
    int hk = t & 511;
    int h = hk >> 7, k = hk & 127;
    const float* W = which ? W_src : W_tgt;
    const float* att = which ? att_src : att_tgt;
    float acc = 0.f;
#pragma unroll 4
    for (int d = 0; d < 128; ++d)
      acc += att[h * 128 + d] * W[(h * 128 + d) * 128 + k];
    ws_c[(which ? 512 : 0) + hk] = acc;
  } else if (blk < 196) {
    int i = (blk - 4) * 256 + tid;  // 0..49151
    int r = i >> 7, c = i & 127;
    float v = (r < 256) ? W_gv[i] : W_out[i - 32768];
    int mat = (r < 128) ? 0 : ((r < 256) ? 1 : 2);
    int n = r & 127, kg = c >> 3, j = c & 7;
    wpP[mat * 16384 + (kg * 128 + n) * 8 + j] = f2bf(v);
  } else {
    int i = (blk - 196) * 256 + tid;  // 0..65535
    int n = i >> 7, c = i & 127;
    int kg = c >> 3, j = c & 7;
    W_srcP[(kg * 512 + n) * 8 + j] = f2bf(W_src[i]);
  }
}

// ---------------- K1: a_tgtT[b][h][t], a_srcT[b][h][s] (fp32) ----------------
__global__ __launch_bounds__(256) void k_avec(
    const float* __restrict__ x_target,
    const float* __restrict__ x_source,
    const float* __restrict__ ws_c,
    float* __restrict__ a_tgtT, float* __restrict__ a_srcT) {
  int wave = threadIdx.x >> 6, lane = threadIdx.x & 63;
  int row = blockIdx.x * 4 + wave;  // 0..16383
  int is_src = row >> 13;
  int r = row & 8191;
  const float* xp = (is_src ? x_source : x_target) + (size_t)r * 128;
  float2 xv = *(const float2*)(xp + lane * 2);
  const float* c = ws_c + (is_src ? 512 : 0);
  float* out = is_src ? a_srcT : a_tgtT;
#pragma unroll
  for (int h = 0; h < 4; ++h) {
    float p = xv.x * c[h * 128 + lane * 2] + xv.y * c[h * 128 + lane * 2 + 1];
#pragma unroll
    for (int off = 32; off; off >>= 1) p += __shfl_xor(p, off);
    if (lane == 0) out[(((r >> 10) * 4 + h) << 10) | (r & 1023)] = p;
  }
}

// ---------------- K2: h_srcP[b][h][s/8][d][8] = (x_source @ W_src^T) tiled bf16 ----
__global__ __launch_bounds__(256) void k_hsrc(
    const float* __restrict__ x_source,
    const unsigned short* __restrict__ W_srcP,
    unsigned short* __restrict__ h_srcP) {
  __shared__ unsigned short As[128][136];  // bf16 A tile; reused as transposed C tile
  int mt = blockIdx.x >> 2, nt = blockIdx.x & 3;
  int nbase = nt * 128;
  int b = mt >> 3, sbase = (mt & 7) * 128;
  int tid = threadIdx.x;
#pragma unroll
  for (int c = tid; c < 2048; c += 256) {
    int r = c >> 4, c8 = (c & 15) * 8;
    const float* src = x_source + ((size_t)(mt * 128 + r)) * 128 + c8;
    *(s16x8*)&As[r][c8] = pack8(*(const float4*)src, *(const float4*)(src + 4));
  }
  __syncthreads();
  int w = tid >> 6, lane = tid & 63, tl = lane & 31, q = lane >> 5;
  int wm = w >> 1, wn = w & 1;
  f32x16 acc00 = zero16(), acc01 = zero16(), acc10 = zero16(), acc11 = zero16();
#pragma unroll
  for (int kk = 0; kk < 8; ++kk) {
    int k = kk * 16 + q * 8;
    int kg = kk * 2 + q;
    s16x8 a0 = *(const s16x8*)&As[wm * 64 + tl][k];
    s16x8 a1 = *(const s16x8*)&As[wm * 64 + 32 + tl][k];
    s16x8 b0 = *(const s16x8*)(W_srcP + (size_t)(kg * 512 + nbase + wn * 64 + tl) * 8);
    s16x8 b1 = *(const s16x8*)(W_srcP + (size_t)(kg * 512 + nbase + wn * 64 + 32 + tl) * 8);
    acc00 = mfma_bf16(a0, b0, acc00);
    acc01 = mfma_bf16(a0, b1, acc01);
    acc10 = mfma_bf16(a1, b0, acc10);
    acc11 = mfma_bf16(a1, b1, acc11);
  }
  __syncthreads();
#pragma unroll
  for (int r = 0; r < 16; ++r) {
    int rp = (r & 3) + 8 * (r >> 2) + 4 * q;
    As[wn * 64 + tl][wm * 64 + rp] = f2bf(acc00[r]);
    As[wn * 64 + 32 + tl][wm * 64 + rp] = f2bf(acc01[r]);
    As[wn * 64 + tl][wm * 64 + 32 + rp] = f2bf(acc10[r]);
    As[wn * 64 + 32 + tl][wm * 64 + 32 + rp] = f2bf(acc11[r]);
  }
  __syncthreads();
  // store tiled: h_srcP[(b*4+h)<<17 | sg*1024 | d*8 + j]; coalesced across d
  {
    int hh = nbase >> 7;
    size_t base = ((size_t)(b * 4 + hh)) << 17;
#pragma unroll
    for (int c = tid; c < 2048; c += 256) {
      int d = c & 127, sgl = c >> 7;
      *(uint4*)(h_srcP + base + (size_t)((sbase >> 3) + sgl) * 1024 + d * 8) =
          *(const uint4*)&As[d][sgl * 8];
    }
  }
}

// ---------------- K3: fused stats + attention einsum + head-mean + bias ----------------
// grid 256 = b(&7, XCD-swizzle) x t-tile(>>3); 1024 threads = 16 waves (head, s-quarter)
__global__ __launch_bounds__(1024, 4) void k_attn(
    const float* __restrict__ adj,
    const unsigned short* __restrict__ h_srcP,
    const float* __restrict__ a_tgtT, const float* __restrict__ a_srcT,
    const float* __restrict__ gat_bias,
    float* __restrict__ out_mean) {
  __shared__ float asb[4096];          // a_src[h][s]
  __shared__ float red[4][32][128];    // per-head partial out
  __shared__ unsigned int bmask[32][33];
  __shared__ float atb[4][32], mb[4][32], scb[4][32];
  __shared__ float zpart[4][4][32];

  int b = blockIdx.x & 7, tt = blockIdx.x >> 3;
  int tbase = tt * 32;
  int tid = threadIdx.x;
  int w = tid >> 6, lane = tid & 63;

  // P0: stage a_src
  {
    float4 v = *(const float4*)(a_srcT + (b << 12) + tid * 4);
    *(float4*)&asb[tid * 4] = v;
  }
  __syncthreads();

  // P1: stream adj -> bitmask + masked max of a_src per (row, head)
  {
    int half = lane >> 5, sl = lane & 31;
    int r = 2 * w + half;
    int t = tbase + r;
    const float* adjrow = adj + ((size_t)(b * 1024 + t) << 10);
    float at[4], amax[4];
#pragma unroll
    for (int h = 0; h < 4; ++h) {
      at[h] = a_tgtT[((b * 4 + h) << 10) | t];
      amax[h] = -3e38f;
    }
#pragma unroll 4
    for (int j = 0; j < 32; ++j) {
      int s = j * 32 + sl;
      float A = adjrow[s];
      bool alive = (A != 0.f);
      unsigned long long bal = __ballot(alive);
      if (sl == 0) bmask[r][j] = (unsigned int)(bal >> (half * 32));
      if (alive) {
#pragma unroll
        for (int h = 0; h < 4; ++h) amax[h] = fmaxf(amax[h], asb[(h << 10) + s]);
      }
    }
#pragma unroll
    for (int off = 1; off < 32; off <<= 1)
#pragma unroll
      for (int h = 0; h < 4; ++h) amax[h] = fmaxf(amax[h], __shfl_xor(amax[h], off));
    if (sl == 0) {
#pragma unroll
      for (int h = 0; h < 4; ++h) {
        atb[h][r] = at[h];
        mb[h][r] = (amax[h] > -1e37f) ? lrelu(at[h] + amax[h]) : 0.f;
      }
    }
  }
  __syncthreads();

  // P2: MFMA loop. wave w: head = w&3, s-quarter = w>>2 (256 s each)
  int head = w & 3, sq = w >> 2;
  int tl = lane & 31, q = lane >> 5;
  float at = atb[head][tl];
  float mm = mb[head][tl];
  f32x16 acc[4];
#pragma unroll
  for (int i = 0; i < 4; ++i) acc[i] = zero16();
  float z = 0.f;
  const float* asl = asb + (head << 10);
  const unsigned short* bbase = h_srcP + (((size_t)(b * 4 + head)) << 17);
#pragma unroll 2
  for (int kk = 0; kk < 16; ++kk) {
    int sA = sq * 256 + kk * 16 + q * 8;
    int sg = sq * 32 + kk * 2 + q;
    const unsigned short* hp = bbase + (size_t)(sg * 128 + tl) * 8;
    s16x8 b0 = *(const s16x8*)(hp);
    s16x8 b1 = *(const s16x8*)(hp + 32 * 8);
    s16x8 b2 = *(const s16x8*)(hp + 64 * 8);
    s16x8 b3 = *(const s16x8*)(hp + 96 * 8);
    float4 as0 = *(const float4*)(asl + sA);
    float4 as1 = *(const float4*)(asl + sA + 4);
    unsigned int wbits = bmask[tl][sA >> 5] >> (sA & 31);
    float asv[8] = {as0.x, as0.y, as0.z, as0.w, as1.x, as1.y, as1.z, as1.w};
    s16x8 af;
#pragma unroll
    for (int j = 0; j < 8; ++j) {
      float e = __expf(lrelu(at + asv[j]) - mm);
      float p = ((wbits >> j) & 1u) ? e : 0.f;
      z += p;
      af[j] = (short)f2bf(p);
    }
    acc[0] = mfma_bf16(af, b0, acc[0]);
    acc[1] = mfma_bf16(af, b1, acc[1]);
    acc[2] = mfma_bf16(af, b2, acc[2]);
    acc[3] = mfma_bf16(af, b3, acc[3]);
  }
  // P3: Z reduction -> sc = 0.25/Z
  z += __shfl_xor(z, 32);
  if (q == 0) zpart[head][sq][tl] = z;
  __syncthreads();
  if (tid < 128) {
    int h = tid >> 5, r = tid & 31;
    float Z = zpart[h][0][r] + zpart[h][1][r] + zpart[h][2][r] + zpart[h][3][r];
    scb[h][r] = (Z > 0.f) ? 0.25f / Z : 0.f;
  }
  // P4: staged accumulator reduction over s-quarters
#pragma unroll
  for (int sqi = 0; sqi < 4; ++sqi) {
    __syncthreads();
    if (sq == sqi) {
#pragma unroll
      for (int dt = 0; dt < 4; ++dt)
#pragma unroll
        for (int r = 0; r < 16; ++r) {
          int rp = (r & 3) + 8 * (r >> 2) + 4 * q;
          if (sqi == 0)
            red[head][rp][dt * 32 + tl] = acc[dt][r];
          else
            red[head][rp][dt * 32 + tl] += acc[dt][r];
        }
    }
  }
  __syncthreads();
  // final: head-mean with per-(t,h) scale + bias
#pragma unroll
  for (int i = tid; i < 4096; i += 1024) {
    int r = i >> 7, d = i & 127;
    float s = red[0][r][d] * scb[0][r] + red[1][r][d] * scb[1][r] +
              red[2][r][d] * scb[2][r] + red[3][r][d] * scb[3][r];
    out_mean[(((size_t)(b * 1024 + tbase + r)) << 7) + d] = s + gat_bias[d];
  }
}

// ---------------- K5: LN1 + SwiGLU FFN + LN2 -> fp32 out ----------------
__global__ __launch_bounds__(256) void k_ffn(
    const float* __restrict__ x_target,
    const float* __restrict__ out_mean,
    const float* __restrict__ ln1_g, const float* __restrict__ ln1_b,
    const unsigned short* __restrict__ wpP,  // tiled bf16: val, gate, out @ 16384 each
    const float* __restrict__ ln2_g, const float* __restrict__ ln2_b,
    float* __restrict__ out) {
  __shared__ unsigned short x1s[32][136];
  __shared__ float x1f[32][128];
  __shared__ unsigned short hids[32][136];
  __shared__ float yred[32][128];
  int tid = threadIdx.x;
  int rbase = blockIdx.x * 32;
  int row = tid >> 3, j8 = tid & 7, k0 = j8 * 16;
  size_t gr = (size_t)rbase + row;
  {
    const float* xp = x_target + gr * 128 + k0;
    const float* op = out_mean + gr * 128 + k0;
    float u[16];
#pragma unroll
    for (int i = 0; i < 16; i += 4) {
      float4 xa = *(const float4*)(xp + i);
      float4 oa = *(const float4*)(op + i);
      u[i] = xa.x + oa.x; u[i + 1] = xa.y + oa.y;
      u[i + 2] = xa.z + oa.z; u[i + 3] = xa.w + oa.w;
    }
    float s = 0.f, ss = 0.f;
#pragma unroll
    for (int i = 0; i < 16; ++i) { s += u[i]; ss += u[i] * u[i]; }
#pragma unroll
    for (int off = 1; off < 8; off <<= 1) { s += __shfl_xor(s, off); ss += __shfl_xor(ss, off); }
    float mu = s * (1.f / 128.f);
    float var = ss * (1.f / 128.f) - mu * mu;
    float rstd = rsqrtf(var + 1e-5f);
#pragma unroll
    for (int i = 0; i < 16; ++i) {
      float xv = (u[i] - mu) * rstd * ln1_g[k0 + i] + ln1_b[k0 + i];
      x1s[row][k0 + i] = f2bf(xv);
      x1f[row][k0 + i] = xv;
    }
  }
  __syncthreads();
  int w = tid >> 6, lane = tid & 63, tl = lane & 31, q = lane >> 5;
  f32x16 accv = zero16(), accg = zero16();
#pragma unroll
  for (int kk = 0; kk < 8; ++kk) {
    int k = kk * 16 + q * 8;
    int kg = kk * 2 + q;
    s16x8 a = *(const s16x8*)&x1s[tl][k];
    s16x8 bvf = *(const s16x8*)(wpP + (size_t)(kg * 128 + w * 32 + tl) * 8);
    s16x8 bgf = *(const s16x8*)(wpP + 16384 + (size_t)(kg * 128 + w * 32 + tl) * 8);
    accv = mfma_bf16(a, bvf, accv);
    accg = mfma_bf16(a, bgf, accg);
  }
#pragma unroll
  for (int r = 0; r < 16; ++r) {
    int m = (r & 3) + 8 * (r >> 2) + 4 * q;
    float g = accg[r];
    float sig = 1.f / (1.f + __expf(-g));
    hids[m][w * 32 + tl] = f2bf(accv[r] * g * sig);
  }
  __syncthreads();
  f32x16 acco = zero16();
#pragma unroll
  for (int kk = 0; kk < 8; ++kk) {
    int k = kk * 16 + q * 8;
    int kg = kk * 2 + q;
    s16x8 bof = *(const s16x8*)(wpP + 32768 + (size_t)(kg * 128 + w * 32 + tl) * 8);
    acco = mfma_bf16(*(const s16x8*)&hids[tl][k], bof, acco);
  }
#pragma unroll
  for (int r = 0; r < 16; ++r) {
    int m = (r & 3) + 8 * (r >> 2) + 4 * q;
    yred[m][w * 32 + tl] = x1f[m][w * 32 + tl] + acco[r];
  }
  __syncthreads();
  {
    float y[16];
#pragma unroll
    for (int i = 0; i < 16; ++i) y[i] = yred[row][k0 + i];
    float s = 0.f, ss = 0.f;
#pragma unroll
    for (int i = 0; i < 16; ++i) { s += y[i]; ss += y[i] * y[i]; }
#pragma unroll
    for (int off = 1; off < 8; off <<= 1) { s += __shfl_xor(s, off); ss += __shfl_xor(ss, off); }
    float mu = s * (1.f / 128.f);
    float var = ss * (1.f / 128.f) - mu * mu;
    float rstd = rsqrtf(var + 1e-5f);
#pragma unroll
    for (int i = 0; i < 16; i += 4) {
      float4 o;
      o.x = (y[i] - mu) * rstd * ln2_g[k0 + i] + ln2_b[k0 + i];
      o.y = (y[i + 1] - mu) * rstd * ln2_g[k0 + i + 1] + ln2_b[k0 + i + 1];
      o.z = (y[i + 2] - mu) * rstd * ln2_g[k0 + i + 2] + ln2_b[k0 + i + 2];
      o.w = (y[i + 3] - mu) * rstd * ln2_g[k0 + i + 3] + ln2_b[k0 + i + 3];
      *(float4*)(out + gr * 128 + k0 + i) = o;
    }
  }
}

// ---------------- launch ----------------
extern "C" void kernel_launch(void* const* d_in, const int* in_sizes, int n_in,
                              void* d_out, int out_size, void* d_ws, size_t ws_size,
                              hipStream_t stream) {
  const float* x_target = (const float*)d_in[0];
  const float* adj      = (const float*)d_in[1];
  const float* x_source = (const float*)d_in[2];
  const float* W_src    = (const float*)d_in[3];
  const float* W_tgt    = (const float*)d_in[4];
  const float* att_src  = (const float*)d_in[5];
  const float* att_tgt  = (const float*)d_in[6];
  const float* gat_bias = (const float*)d_in[7];
  const float* ln1_g    = (const float*)d_in[8];
  const float* ln1_b    = (const float*)d_in[9];
  const float* W_gv     = (const float*)d_in[10];
  const float* W_out    = (const float*)d_in[11];
  const float* ln2_g    = (const float*)d_in[12];
  const float* ln2_b    = (const float*)d_in[13];

  float* ws_f = (float*)d_ws;
  const size_t OFF_C   = 0;        // 1024 f
  const size_t OFF_ATG = 1024;     // a_tgtT [8][4][1024]
  const size_t OFF_ASR = 33792;    // a_srcT [8][4][1024]
  const size_t OFF_OM  = 66560;    // out_mean [8192][128]
  unsigned short* h_srcP = (unsigned short*)(ws_f + OFF_OM + (size_t)8192 * 128);
  unsigned short* wpP    = h_srcP + (size_t)8 * 4 * 131072;  // 49152 bf16
  unsigned short* W_srcP = wpP + 49152;                      // 65536 bf16

  k_prep<<<452, 256, 0, stream>>>(W_tgt, W_src, att_tgt, att_src, W_gv, W_out,
                                  ws_f + OFF_C, wpP, W_srcP);
  k_avec<<<4096, 256, 0, stream>>>(x_target, x_source, ws_f + OFF_C,
                                   ws_f + OFF_ATG, ws_f + OFF_ASR);
  k_hsrc<<<256, 256, 0, stream>>>(x_source, W_srcP, h_srcP);
  k_attn<<<256, 1024, 0, stream>>>(adj, h_srcP, ws_f + OFF_ATG, ws_f + OFF_ASR,
                                   gat_bias, ws_f + OFF_OM);
  k_ffn<<<256, 256, 0, stream>>>(x_target, ws_f + OFF_OM, ln1_g, ln1_b,
                                 wpP, ln2_g, ln2_b, (float*)d_out);
}

// Round 5
// 157.748 us; speedup vs baseline: 1.3515x; 1.0360x over previous
//
#include <hip/hip_runtime.h>
#include <stdint.h>

// Shapes: B=8, Nt=Ns=1024, D=128, H=4. All I/O float32.

typedef float f32x16 __attribute__((ext_vector_type(16)));
typedef short s16x8 __attribute__((ext_vector_type(8)));
typedef __bf16 bf16x8 __attribute__((ext_vector_type(8)));

__device__ __forceinline__ f32x16 mfma_bf16(s16x8 a, s16x8 b, f32x16 c) {
  return __builtin_amdgcn_mfma_f32_32x32x16_bf16(
      __builtin_bit_cast(bf16x8, a), __builtin_bit_cast(bf16x8, b), c, 0, 0, 0);
}

__device__ __forceinline__ unsigned short f2bf(float f) {
  union { float f; unsigned int i; } v; v.f = f;
  return (unsigned short)((v.i + 0x8000u) >> 16);
}
__device__ __forceinline__ float bf2f(unsigned short u) {
  union { unsigned int i; float f; } v; v.i = ((unsigned int)u) << 16; return v.f;
}
__device__ __forceinline__ s16x8 pack8(float4 a, float4 b) {
  s16x8 r;
  r[0] = (short)f2bf(a.x); r[1] = (short)f2bf(a.y);
  r[2] = (short)f2bf(a.z); r[3] = (short)f2bf(a.w);
  r[4] = (short)f2bf(b.x); r[5] = (short)f2bf(b.y);
  r[6] = (short)f2bf(b.z); r[7] = (short)f2bf(b.w);
  return r;
}
__device__ __forceinline__ f32x16 zero16() {
  f32x16 z;
#pragma unroll
  for (int i = 0; i < 16; ++i) z[i] = 0.f;
  return z;
}

// ---------------- K_prep: cvec partials + FFN weight pack + W_src pack ----------------
__global__ __launch_bounds__(256) void k_prep(
    const float* __restrict__ W_tgt, const float* __restrict__ W_src,
    const float* __restrict__ att_tgt, const float* __restrict__ att_src,
    const float* __restrict__ W_gv, const float* __restrict__ W_out,
    float* __restrict__ ws_cp, unsigned short* __restrict__ wpP,
    unsigned short* __restrict__ W_srcP) {
  int blk = blockIdx.x, tid = threadIdx.x;
  if (blk < 32) {
    // cvec partials: ws_cp[which][h][8][128]
    int which = blk >> 4, h = (blk >> 2) & 3, dc = blk & 3;
    int k = tid & 127, dh = tid >> 7;
    int dbase = dc * 32 + dh * 16;
    const float* W = which ? W_src : W_tgt;
    const float* att = which ? att_src : att_tgt;
    float acc = 0.f;
#pragma unroll
    for (int i = 0; i < 16; ++i) {
      int d = dbase + i;
      acc += att[h * 128 + d] * W[(h * 128 + d) * 128 + k];
    }
    ws_cp[((which * 4 + h) * 8 + dc * 2 + dh) * 128 + k] = acc;
  } else if (blk < 224) {
    int i = (blk - 32) * 256 + tid;  // 0..49151
    int r = i >> 7, c = i & 127;
    float v = (r < 256) ? W_gv[i] : W_out[i - 32768];
    int mat = (r < 128) ? 0 : ((r < 256) ? 1 : 2);
    int n = r & 127, kg = c >> 3, j = c & 7;
    wpP[mat * 16384 + (kg * 128 + n) * 8 + j] = f2bf(v);
  } else {
    int i = (blk - 224) * 256 + tid;  // 0..65535
    int n = i >> 7, c = i & 127;
    int kg = c >> 3, j = c & 7;
    W_srcP[(kg * 512 + n) * 8 + j] = f2bf(W_src[i]);
  }
}

// ---------------- K_mid: avec (a_tgt + ES/ES2) | adj bitmask | h_src GEMM ----------------
__global__ __launch_bounds__(256) void k_mid(
    const float* __restrict__ x_target, const float* __restrict__ x_source,
    const float* __restrict__ adj, const float* __restrict__ ws_cp,
    const unsigned short* __restrict__ W_srcP,
    float* __restrict__ a_tgtT, float* __restrict__ esrc,
    unsigned long long* __restrict__ abits,
    unsigned short* __restrict__ h_srcP) {
  __shared__ unsigned short As[128][136];
  int blk = blockIdx.x, tid = threadIdx.x;
  int w = tid >> 6, lane = tid & 63;
  if (blk < 4096) {
    // ---- avec: rows 0..16383 (tgt then src) ----
    int row = blk * 4 + w;
    int is_src = row >> 13;
    int r = row & 8191;
    float* csum = (float*)&As[0][0];  // [4][128]
#pragma unroll
    for (int rep = 0; rep < 2; ++rep) {
      int v = tid + rep * 256;
      float s = 0.f;
#pragma unroll
      for (int j = 0; j < 8; ++j)
        s += ws_cp[(is_src * 4 + (v >> 7)) * 1024 + j * 128 + (v & 127)];
      csum[v] = s;
    }
    __syncthreads();
    const float* xp = (is_src ? x_source : x_target) + (size_t)r * 128;
    float2 xv = *(const float2*)(xp + lane * 2);
#pragma unroll
    for (int h = 0; h < 4; ++h) {
      float p = xv.x * csum[h * 128 + lane * 2] + xv.y * csum[h * 128 + lane * 2 + 1];
#pragma unroll
      for (int off = 32; off; off >>= 1) p += __shfl_xor(p, off);
      if (lane == 0) {
        int idx = (((r >> 10) * 4 + h) << 10) | (r & 1023);
        if (is_src) {
          float2 e = make_float2(__expf(p), __expf(0.2f * p));
          *(float2*)&esrc[(size_t)idx * 2] = e;
        } else {
          a_tgtT[idx] = p;
        }
      }
    }
  } else if (blk < 6144) {
    // ---- adj -> bitmask ----
    int row = (blk - 4096) * 4 + w;  // 0..8191
    const float* ar = adj + (size_t)row * 1024;
#pragma unroll 4
    for (int it = 0; it < 16; ++it) {
      float A = ar[it * 64 + lane];
      unsigned long long bal = __ballot(A != 0.f);
      if (lane == 0) abits[row * 16 + it] = bal;
    }
  } else {
    // ---- h_src GEMM -> h_srcP[b*4+h][s/8][d][8] bf16 ----
    int blk2 = blk - 6144;
    int mt = blk2 >> 2, nt = blk2 & 3;
    int nbase = nt * 128;
    int b = mt >> 3, sbase = (mt & 7) * 128;
#pragma unroll
    for (int c = tid; c < 2048; c += 256) {
      int r = c >> 4, c8 = (c & 15) * 8;
      const float* src = x_source + ((size_t)(mt * 128 + r)) * 128 + c8;
      *(s16x8*)&As[r][c8] = pack8(*(const float4*)src, *(const float4*)(src + 4));
    }
    __syncthreads();
    int tl = lane & 31, q = lane >> 5;
    int wm = w >> 1, wn = w & 1;
    f32x16 acc00 = zero16(), acc01 = zero16(), acc10 = zero16(), acc11 = zero16();
#pragma unroll
    for (int kk = 0; kk < 8; ++kk) {
      int k = kk * 16 + q * 8;
      int kg = kk * 2 + q;
      s16x8 a0 = *(const s16x8*)&As[wm * 64 + tl][k];
      s16x8 a1 = *(const s16x8*)&As[wm * 64 + 32 + tl][k];
      s16x8 b0 = *(const s16x8*)(W_srcP + (size_t)(kg * 512 + nbase + wn * 64 + tl) * 8);
      s16x8 b1 = *(const s16x8*)(W_srcP + (size_t)(kg * 512 + nbase + wn * 64 + 32 + tl) * 8);
      acc00 = mfma_bf16(a0, b0, acc00);
      acc01 = mfma_bf16(a0, b1, acc01);
      acc10 = mfma_bf16(a1, b0, acc10);
      acc11 = mfma_bf16(a1, b1, acc11);
    }
    __syncthreads();
#pragma unroll
    for (int r = 0; r < 16; ++r) {
      int rp = (r & 3) + 8 * (r >> 2) + 4 * q;
      As[wn * 64 + tl][wm * 64 + rp] = f2bf(acc00[r]);
      As[wn * 64 + 32 + tl][wm * 64 + rp] = f2bf(acc01[r]);
      As[wn * 64 + tl][wm * 64 + 32 + rp] = f2bf(acc10[r]);
      As[wn * 64 + 32 + tl][wm * 64 + 32 + rp] = f2bf(acc11[r]);
    }
    __syncthreads();
    int hh = nbase >> 7;
    size_t base = ((size_t)(b * 4 + hh)) << 17;
#pragma unroll
    for (int c = tid; c < 2048; c += 256) {
      int d = c & 127, sgl = c >> 7;
      *(uint4*)(h_srcP + base + (size_t)((sbase >> 3) + sgl) * 1024 + d * 8) =
          *(const uint4*)&As[d][sgl * 8];
    }
  }
}

// ---------------- K_attn: per-(b,head,t-tile) attention, separable exp ----------------
// grid 1024 = tt(32) x bh(32, low bits for XCD L2 locality); 4 waves = s-quarters.
__global__ __launch_bounds__(256, 4) void k_attn(
    const unsigned short* __restrict__ h_srcP,
    const float* __restrict__ a_tgtT, const float* __restrict__ esrc,
    const unsigned int* __restrict__ abits32,
    unsigned short* __restrict__ out_head) {
  __shared__ float smem[4096];         // phase A: es[s]{ES,ES2} 2048f; phase B: red[32][128]
  __shared__ unsigned int bmask[32][33];
  __shared__ float eab[32], ea2b[32], scb[32];
  __shared__ float zpart[4][32];
  int bh = blockIdx.x & 31, tt = blockIdx.x >> 5;
  int b = bh >> 2;
  int tbase = tt * 32;
  int tid = threadIdx.x, w = tid >> 6, lane = tid & 63;
  // stage ES/ES2 (interleaved float2 per s)
  {
    const float* ep = esrc + ((size_t)bh << 11);
    *(float4*)&smem[tid * 8] = *(const float4*)(ep + tid * 8);
    *(float4*)&smem[tid * 8 + 4] = *(const float4*)(ep + tid * 8 + 4);
  }
  // stage bitmask rows
  {
    int r = tid >> 3, c = tid & 7;
    uint4 v = *(const uint4*)(abits32 + ((size_t)(b * 1024 + tbase + r)) * 32 + c * 4);
    bmask[r][c * 4] = v.x; bmask[r][c * 4 + 1] = v.y;
    bmask[r][c * 4 + 2] = v.z; bmask[r][c * 4 + 3] = v.w;
  }
  if (tid < 32) {
    float at = a_tgtT[((size_t)bh << 10) + tbase + tid];
    eab[tid] = __expf(at);
    ea2b[tid] = __expf(0.2f * at);
  }
  __syncthreads();
  int sq = w, tl = lane & 31, q = lane >> 5;
  float EA = eab[tl], EA2 = ea2b[tl];
  f32x16 acc[4];
#pragma unroll
  for (int i = 0; i < 4; ++i) acc[i] = zero16();
  float z = 0.f;
  const unsigned short* bbase = h_srcP + ((size_t)bh << 17);
#pragma unroll 2
  for (int kk = 0; kk < 16; ++kk) {
    int sA = sq * 256 + kk * 16 + q * 8;
    const unsigned short* hp = bbase + (size_t)((sA >> 3) * 128 + tl) * 8;
    s16x8 b0 = *(const s16x8*)hp;
    s16x8 b1 = *(const s16x8*)(hp + 256);
    s16x8 b2 = *(const s16x8*)(hp + 512);
    s16x8 b3 = *(const s16x8*)(hp + 768);
    unsigned int wbits = bmask[tl][sA >> 5] >> (sA & 31);
    const float4* ev = (const float4*)&smem[sA * 2];
    float4 e0 = ev[0], e1 = ev[1], e2 = ev[2], e3 = ev[3];
    int4 afw;
#define PAIR(EV, J0, OUT)                                              \
  {                                                                    \
    float q1a = EA * EV.x, q0a = EA2 * EV.y;                           \
    float pa = (q1a >= 1.f) ? q1a : q0a;                               \
    unsigned pau = __float_as_uint(pa) & (0u - ((wbits >> (J0)) & 1u)); \
    float q1b = EA * EV.z, q0b = EA2 * EV.w;                           \
    float pb = (q1b >= 1.f) ? q1b : q0b;                               \
    unsigned pbu = __float_as_uint(pb) & (0u - ((wbits >> (J0 + 1)) & 1u)); \
    z += __uint_as_float(pau) + __uint_as_float(pbu);                  \
    OUT = (int)__builtin_amdgcn_perm(pbu + 0x8000u, pau + 0x8000u, 0x07060302u); \
  }
    PAIR(e0, 0, afw.x)
    PAIR(e1, 2, afw.y)
    PAIR(e2, 4, afw.z)
    PAIR(e3, 6, afw.w)
#undef PAIR
    s16x8 af = __builtin_bit_cast(s16x8, afw);
    acc[0] = mfma_bf16(af, b0, acc[0]);
    acc[1] = mfma_bf16(af, b1, acc[1]);
    acc[2] = mfma_bf16(af, b2, acc[2]);
    acc[3] = mfma_bf16(af, b3, acc[3]);
  }
  z += __shfl_xor(z, 32);
  if (q == 0) zpart[sq][tl] = z;
  __syncthreads();  // also: done reading smem-es
  if (tid < 32) {
    float Z = zpart[0][tid] + zpart[1][tid] + zpart[2][tid] + zpart[3][tid];
    scb[tid] = (Z > 0.f) ? 0.25f / Z : 0.f;
  }
  float (*red)[128] = (float(*)[128])smem;
#pragma unroll
  for (int sqi = 0; sqi < 4; ++sqi) {
    __syncthreads();
    if (sq == sqi) {
#pragma unroll
      for (int dt = 0; dt < 4; ++dt)
#pragma unroll
        for (int r = 0; r < 16; ++r) {
          int rp = (r & 3) + 8 * (r >> 2) + 4 * q;
          if (sqi == 0)
            red[rp][dt * 32 + tl] = acc[dt][r];
          else
            red[rp][dt * 32 + tl] += acc[dt][r];
        }
    }
  }
  __syncthreads();
  // scaled bf16 store: out_head[h][b*1024+t][d]
  {
    int idx = tid * 16;
    int r = idx >> 7, d0 = idx & 127;
    float sc = scb[r];
    s16x8 o0, o1;
#pragma unroll
    for (int i = 0; i < 8; ++i) {
      o0[i] = (short)f2bf(red[r][d0 + i] * sc);
      o1[i] = (short)f2bf(red[r][d0 + 8 + i] * sc);
    }
    size_t base = ((size_t)(bh & 3)) * 1048576 +
                  ((size_t)(b * 1024 + tbase + r)) * 128 + d0;
    *(s16x8*)(out_head + base) = o0;
    *(s16x8*)(out_head + base + 8) = o1;
  }
}

// ---------------- K_ffn: head-sum + bias + LN1 + SwiGLU FFN + LN2 ----------------
__global__ __launch_bounds__(256) void k_ffn(
    const float* __restrict__ x_target,
    const unsigned short* __restrict__ out_head,
    const float* __restrict__ gat_bias,
    const float* __restrict__ ln1_g, const float* __restrict__ ln1_b,
    const unsigned short* __restrict__ wpP,
    const float* __restrict__ ln2_g, const float* __restrict__ ln2_b,
    float* __restrict__ out) {
  __shared__ unsigned short x1s[32][136];
  __shared__ float x1f[32][128];
  __shared__ unsigned short hids[32][136];
  __shared__ float yred[32][128];
  int tid = threadIdx.x;
  int rbase = blockIdx.x * 32;
  int row = tid >> 3, j8 = tid & 7, k0 = j8 * 16;
  size_t gr = (size_t)rbase + row;
  {
    const float* xp = x_target + gr * 128 + k0;
    float u[16];
#pragma unroll
    for (int i = 0; i < 16; i += 4) {
      float4 xa = *(const float4*)(xp + i);
      float4 ba = *(const float4*)(gat_bias + k0 + i);
      u[i] = xa.x + ba.x; u[i + 1] = xa.y + ba.y;
      u[i + 2] = xa.z + ba.z; u[i + 3] = xa.w + ba.w;
    }
#pragma unroll
    for (int h = 0; h < 4; ++h) {
      const unsigned short* ohp = out_head + (size_t)h * 1048576 + gr * 128 + k0;
      s16x8 pa = *(const s16x8*)(ohp);
      s16x8 pb = *(const s16x8*)(ohp + 8);
#pragma unroll
      for (int i = 0; i < 8; ++i) {
        u[i] += bf2f((unsigned short)pa[i]);
        u[i + 8] += bf2f((unsigned short)pb[i]);
      }
    }
    float s = 0.f, ss = 0.f;
#pragma unroll
    for (int i = 0; i < 16; ++i) { s += u[i]; ss += u[i] * u[i]; }
#pragma unroll
    for (int off = 1; off < 8; off <<= 1) { s += __shfl_xor(s, off); ss += __shfl_xor(ss, off); }
    float mu = s * (1.f / 128.f);
    float var = ss * (1.f / 128.f) - mu * mu;
    float rstd = rsqrtf(var + 1e-5f);
#pragma unroll
    for (int i = 0; i < 16; ++i) {
      float xv = (u[i] - mu) * rstd * ln1_g[k0 + i] + ln1_b[k0 + i];
      x1s[row][k0 + i] = f2bf(xv);
      x1f[row][k0 + i] = xv;
    }
  }
  __syncthreads();
  int w = tid >> 6, lane = tid & 63, tl = lane & 31, q = lane >> 5;
  f32x16 accv = zero16(), accg = zero16();
#pragma unroll
  for (int kk = 0; kk < 8; ++kk) {
    int k = kk * 16 + q * 8;
    int kg = kk * 2 + q;
    s16x8 a = *(const s16x8*)&x1s[tl][k];
    s16x8 bvf = *(const s16x8*)(wpP + (size_t)(kg * 128 + w * 32 + tl) * 8);
    s16x8 bgf = *(const s16x8*)(wpP + 16384 + (size_t)(kg * 128 + w * 32 + tl) * 8);
    accv = mfma_bf16(a, bvf, accv);
    accg = mfma_bf16(a, bgf, accg);
  }
#pragma unroll
  for (int r = 0; r < 16; ++r) {
    int m = (r & 3) + 8 * (r >> 2) + 4 * q;
    float g = accg[r];
    float sig = 1.f / (1.f + __expf(-g));
    hids[m][w * 32 + tl] = f2bf(accv[r] * g * sig);
  }
  __syncthreads();
  f32x16 acco = zero16();
#pragma unroll
  for (int kk = 0; kk < 8; ++kk) {
    int k = kk * 16 + q * 8;
    int kg = kk * 2 + q;
    s16x8 bof = *(const s16x8*)(wpP + 32768 + (size_t)(kg * 128 + w * 32 + tl) * 8);
    acco = mfma_bf16(*(const s16x8*)&hids[tl][k], bof, acco);
  }
#pragma unroll
  for (int r = 0; r < 16; ++r) {
    int m = (r & 3) + 8 * (r >> 2) + 4 * q;
    yred[m][w * 32 + tl] = x1f[m][w * 32 + tl] + acco[r];
  }
  __syncthreads();
  {
    float y[16];
#pragma unroll
    for (int i = 0; i < 16; ++i) y[i] = yred[row][k0 + i];
    float s = 0.f, ss = 0.f;
#pragma unroll
    for (int i = 0; i < 16; ++i) { s += y[i]; ss += y[i] * y[i]; }
#pragma unroll
    for (int off = 1; off < 8; off <<= 1) { s += __shfl_xor(s, off); ss += __shfl_xor(ss, off); }
    float mu = s * (1.f / 128.f);
    float var = ss * (1.f / 128.f) - mu * mu;
    float rstd = rsqrtf(var + 1e-5f);
#pragma unroll
    for (int i = 0; i < 16; i += 4) {
      float4 o;
      o.x = (y[i] - mu) * rstd * ln2_g[k0 + i] + ln2_b[k0 + i];
      o.y = (y[i + 1] - mu) * rstd * ln2_g[k0 + i + 1] + ln2_b[k0 + i + 1];
      o.z = (y[i + 2] - mu) * rstd * ln2_g[k0 + i + 2] + ln2_b[k0 + i + 2];
      o.w = (y[i + 3] - mu) * rstd * ln2_g[k0 + i + 3] + ln2_b[k0 + i + 3];
      *(float4*)(out + gr * 128 + k0 + i) = o;
    }
  }
}

// ---------------- launch ----------------
extern "C" void kernel_launch(void* const* d_in, const int* in_sizes, int n_in,
                              void* d_out, int out_size, void* d_ws, size_t ws_size,
                              hipStream_t stream) {
  const float* x_target = (const float*)d_in[0];
  const float* adj      = (const float*)d_in[1];
  const float* x_source = (const float*)d_in[2];
  const float* W_src    = (const float*)d_in[3];
  const float* W_tgt    = (const float*)d_in[4];
  const float* att_src  = (const float*)d_in[5];
  const float* att_tgt  = (const float*)d_in[6];
  const float* gat_bias = (const float*)d_in[7];
  const float* ln1_g    = (const float*)d_in[8];
  const float* ln1_b    = (const float*)d_in[9];
  const float* W_gv     = (const float*)d_in[10];
  const float* W_out    = (const float*)d_in[11];
  const float* ln2_g    = (const float*)d_in[12];
  const float* ln2_b    = (const float*)d_in[13];

  float* ws_f = (float*)d_ws;
  // workspace layout (float-element offsets)
  const size_t OFF_CP = 0;        // ws_cp [2][4][8][128] = 8192 f
  const size_t OFF_AT = 8192;     // a_tgtT [8][4][1024] = 32768 f
  const size_t OFF_ES = 40960;    // esrc float2 [8][4][1024] = 65536 f
  const size_t OFF_AB = 106496;   // abits u64 [8192][16] = 262144 f
  const size_t OFF_OH = 368640;   // out_head bf16 [4][8192][128] = 2097152 f
  const size_t OFF_HS = 2465792;  // h_srcP bf16 [32][131072]
  unsigned short* h_srcP = (unsigned short*)(ws_f + OFF_HS);
  unsigned short* wpP    = h_srcP + (size_t)4194304;
  unsigned short* W_srcP = wpP + 49152;

  k_prep<<<480, 256, 0, stream>>>(W_tgt, W_src, att_tgt, att_src, W_gv, W_out,
                                  ws_f + OFF_CP, wpP, W_srcP);
  k_mid<<<6400, 256, 0, stream>>>(x_target, x_source, adj, ws_f + OFF_CP, W_srcP,
                                  ws_f + OFF_AT, ws_f + OFF_ES,
                                  (unsigned long long*)(ws_f + OFF_AB), h_srcP);
  k_attn<<<1024, 256, 0, stream>>>(h_srcP, ws_f + OFF_AT, ws_f + OFF_ES,
                                   (const unsigned int*)(ws_f + OFF_AB),
                                   (unsigned short*)(ws_f + OFF_OH));
  k_ffn<<<256, 256, 0, stream>>>(x_target, (const unsigned short*)(ws_f + OFF_OH),
                                 gat_bias, ln1_g, ln1_b, wpP, ln2_g, ln2_b,
                                 (float*)d_out);
}